// Round 13
// baseline (353.496 us; speedup 1.0000x reference)
//
#include <hip/hip_runtime.h>
#include <math.h>

#define IN_C 64
#define HID_C 128
#define OUT_C 64
#define NBK 256   // buckets of 512 nodes: bucket = dst >> 9
#define BD 64     // msplit bin ring depth
#define GS 16     // global atomic counter stride (ints) -> one 64B line each
// packed edge = (src<<9)|(dst&511); sentinel -1 unreachable (src <= N < 2^17).
// CSR rows padded to 8-multiples with dummy src = N (row N of xh/zh zeroed).

typedef __attribute__((ext_vector_type(8))) short bf16x8;   // 8 bf16 (4 VGPRs)
typedef __attribute__((ext_vector_type(4))) float f32x4;    // mfma C/D

__device__ __forceinline__ unsigned short f2bf(float f) {
  unsigned u = __float_as_uint(f);
  u = (u + 0x7FFFu + ((u >> 16) & 1u)) >> 16;  // RNE
  return (unsigned short)u;
}
__device__ __forceinline__ float bf2f(unsigned v) {  // low 16 bits = bf16
  return __uint_as_float(v << 16);
}
__device__ __forceinline__ unsigned pack2(float a, float b) {
  return (unsigned)f2bf(a) | ((unsigned)f2bf(b) << 16);
}

#define RED8(d)                                               \
  a0 += __shfl_xor(a0, d); a1 += __shfl_xor(a1, d);           \
  a2 += __shfl_xor(a2, d); a3 += __shfl_xor(a3, d);           \
  a4 += __shfl_xor(a4, d); a5 += __shfl_xor(a5, d);           \
  a6 += __shfl_xor(a6, d); a7 += __shfl_xor(a7, d);

// ======== fused: bhist (blocks 0..1023) + x->bf16 cast (blocks 1024..3071) ===
__global__ __launch_bounds__(256) void k_xb(const int* __restrict__ dst,
                                            int* __restrict__ bh,
                                            const float4* __restrict__ x4,
                                            uint2* __restrict__ xh2,
                                            int E, int Mreal, int Mtot) {
  __shared__ int hh[NBK];
  int t = threadIdx.x;
  if (blockIdx.x < 1024) {
    hh[t] = 0;
    __syncthreads();
    for (int e = blockIdx.x * 256 + t; e < E; e += 1024 * 256)
      atomicAdd(&hh[dst[e] >> 9], 1);
    __syncthreads();
    if (hh[t]) atomicAdd(&bh[t * GS], hh[t]);
  } else {
    int b = blockIdx.x - 1024;
    for (int i = b * 256 + t; i < Mtot; i += 2048 * 256) {
      uint2 p = {0u, 0u};
      if (i < Mreal) {
        float4 v = x4[i];
        p.x = pack2(v.x, v.y);
        p.y = pack2(v.z, v.w);
      }
      xh2[i] = p;
    }
  }
}

// ======== scan: ebuf chunked-region starts + padded csr starts ========
__global__ __launch_bounds__(256) void k_bscan(const int* __restrict__ bh,
                                               int* __restrict__ bstart,
                                               int* __restrict__ rstart,
                                               int* __restrict__ gcur) {
  __shared__ int s1[NBK], s2[NBK];
  int t = threadIdx.x;
  int cnt = bh[t * GS];
  int region = 16 * min(cnt, (cnt >> 4) + 512);
  int creg = cnt + 4096;
  s1[t] = region; s2[t] = creg;
  __syncthreads();
  for (int off = 1; off < NBK; off <<= 1) {
    int a1 = (t >= off) ? s1[t - off] : 0;
    int a2 = (t >= off) ? s2[t - off] : 0;
    __syncthreads();
    s1[t] += a1; s2[t] += a2;
    __syncthreads();
  }
  int ex1 = s1[t] - region;
  int ex2 = s2[t] - creg;
  bstart[t] = ex1; gcur[t * GS] = ex1; rstart[t] = ex2;
}

// ======== multisplit: transposed ring bins, line-padded cursors, 8-fetch ====
__global__ __launch_bounds__(256) void k_msplit(const int* __restrict__ src,
                                                const int* __restrict__ dst,
                                                int* __restrict__ gcur,
                                                int* __restrict__ ebuf, int E) {
  __shared__ int bcnt[NBK], bhead[NBK];
  __shared__ int bins[BD][NBK];
  int t = threadIdx.x;
  bcnt[t] = 0; bhead[t] = 0;
  int per = (E + gridDim.x - 1) / gridDim.x;
  int e0 = blockIdx.x * per, e1 = min(E, e0 + per);
  int e = e0 + t;
  int pb[8], pv[8]; int pc = 0;
  __syncthreads();
  for (;;) {
    while (pc < 8 && e < e1) {
      int d = dst[e], s = src[e];
      pb[pc] = d >> 9; pv[pc] = (s << 9) | (d & 511);
      pc++; e += 256;
    }
    for (int q = pc - 1; q >= 0; --q) {
      int pos = atomicAdd(&bcnt[pb[q]], 1);
      if (pos < BD) {
        bins[(bhead[pb[q]] + pos) & (BD - 1)][pb[q]] = pv[q];
        pc--;
        if (q != pc) { pb[q] = pb[pc]; pv[q] = pv[pc]; }
      }
    }
    int pending = __syncthreads_count(pc > 0 || e < e1);
    int cntv = min(bcnt[t], BD);
    int head = bhead[t];
    while (cntv >= 16) {
      int base = atomicAdd(&gcur[t * GS], 16);
      int4 o[4];
#pragma unroll
      for (int k = 0; k < 16; ++k)
        ((int*)o)[k] = bins[(head + k) & (BD - 1)][t];
      int4* g = (int4*)(ebuf + base);
      g[0] = o[0]; g[1] = o[1]; g[2] = o[2]; g[3] = o[3];
      head = (head + 16) & (BD - 1);
      cntv -= 16;
    }
    bhead[t] = head;
    bcnt[t] = cntv;
    __syncthreads();
    if (!pending) break;
  }
  int cntv = bcnt[t];
  if (cntv > 0) {
    int head = bhead[t];
    int base = atomicAdd(&gcur[t * GS], 16);
#pragma unroll
    for (int k = 0; k < 16; ++k)
      ebuf[base + k] = (k < cntv) ? bins[(head + k) & (BD - 1)][t] : -1;
  }
}

// ======== per-bucket local CSR (512 nodes/bucket), 8-padded rows ========
__global__ __launch_bounds__(512) void k_localcsr(const int* __restrict__ ebuf,
                                                  const int* __restrict__ bstart,
                                                  const int* __restrict__ gcur,
                                                  const int* __restrict__ rstart,
                                                  int* __restrict__ csr,
                                                  int* __restrict__ row_start,
                                                  int* __restrict__ rend,
                                                  float* __restrict__ invd, int N) {
  __shared__ int lcnt[512], loff[512], lcur[512];
  int t = threadIdx.x, b = blockIdx.x;
  int start = bstart[b], endp = gcur[b * GS], rs = rstart[b];
  lcnt[t] = 0;
  __syncthreads();
  for (int i = start + t; i < endp; i += 512) {
    int pe = ebuf[i];
    if (pe != -1) atomicAdd(&lcnt[pe & 511], 1);
  }
  __syncthreads();
  int v = lcnt[t];
  int pvn = (v + 7) & ~7;
  loff[t] = pvn;
  __syncthreads();
  for (int off = 1; off < 512; off <<= 1) {
    int a = (t >= off) ? loff[t - off] : 0;
    __syncthreads();
    loff[t] += a;
    __syncthreads();
  }
  int ex = loff[t] - pvn;
  lcur[t] = ex;
  int node = (b << 9) + t;
  if (node < N) {
    row_start[node] = rs + ex;
    rend[node] = rs + ex + pvn;
    invd[node] = 1.0f / fmaxf((float)v, 1.0f);
  }
  __syncthreads();
  for (int i = start + t; i < endp; i += 512) {
    int pe = ebuf[i];
    if (pe != -1) {
      int pos = atomicAdd(&lcur[pe & 511], 1);
      csr[rs + pos] = pe >> 9;
    }
  }
  for (int k = ex + v; k < ex + pvn; ++k) csr[rs + k] = N;
}

// ======== fused gather1 + MFMA layer 1 ========
// 256 thr = 4 waves. Wave w owns tile rows 16w..16w+15: gathers its 16 nodes
// into its private sA rows (agg half, stride 72 ush = 144B, b128-aligned),
// then MFMA with A x-half loaded directly from global xh. No per-tile barriers
// (all LDS deps wave-local); one barrier after weight staging.
__global__ __launch_bounds__(256, 3) void k_gl1(
    const unsigned short* __restrict__ xh, const int* __restrict__ csr,
    const int* __restrict__ row_start, const int* __restrict__ rend,
    const float* __restrict__ invd,
    const float* __restrict__ W1l, const float* __restrict__ W1r,
    const float* __restrict__ b1, unsigned short* __restrict__ h, int N) {
  __shared__ __align__(16) unsigned short sW[128 * 136];
  __shared__ __align__(16) unsigned short sA[64 * 72];
  __shared__ float sb[128];
  int t = threadIdx.x;
  for (int i = t; i < 128 * 128; i += 256) {
    int o = i >> 7, k = i & 127;
    float w = (k < 64) ? W1l[o * 64 + k] : W1r[o * 64 + (k - 64)];
    sW[o * 136 + k] = f2bf(w);
  }
  if (t < 128) sb[t] = b1[t];
  int lane = t & 63, qm = lane >> 4, ln = lane & 15;
  int rq = lane >> 3, cq = lane & 7;
  int m0 = (t >> 6) * 16;
  const uint4* xh4 = (const uint4*)xh;
  __syncthreads();

  int ntiles = (N + 63) >> 6;
  for (int tile = blockIdx.x; tile < ntiles; tile += gridDim.x) {
    int base = tile << 6;
    // ---- gather phase: 16 nodes of this wave ----
    for (int n = 0; n < 16; ++n) {
      int node = base + m0 + n;
      if (node >= N) break;
      int j = row_start[node], end = rend[node];
      float a0 = 0, a1 = 0, a2 = 0, a3 = 0, a4 = 0, a5 = 0, a6 = 0, a7 = 0;
#pragma unroll 2
      for (; j < end; j += 8) {
        int s = csr[j + rq];
        uint4 v = xh4[s * 8 + cq];
        a0 += bf2f(v.x & 0xffffu); a1 += bf2f(v.x >> 16);
        a2 += bf2f(v.y & 0xffffu); a3 += bf2f(v.y >> 16);
        a4 += bf2f(v.z & 0xffffu); a5 += bf2f(v.z >> 16);
        a6 += bf2f(v.w & 0xffffu); a7 += bf2f(v.w >> 16);
      }
      RED8(8) RED8(16) RED8(32)
      if (rq == 0) {
        float inv = invd[node];
        uint4 p;
        p.x = pack2(a0 * inv, a1 * inv);
        p.y = pack2(a2 * inv, a3 * inv);
        p.z = pack2(a4 * inv, a5 * inv);
        p.w = pack2(a6 * inv, a7 * inv);
        *(uint4*)(sA + (m0 + n) * 72 + cq * 8) = p;
      }
    }
    // ---- MFMA phase (wave-local dependency on sA) ----
    int arow = m0 + ln;
    int anode = base + arow;
    int axnode = min(anode, N);  // clamp to dummy row for tail garbage rows
    bf16x8 af[4];
    af[0] = *(const bf16x8*)(sA + arow * 72 + qm * 8);
    af[1] = *(const bf16x8*)(sA + arow * 72 + 32 + qm * 8);
    af[2] = *(const bf16x8*)(xh + axnode * 64 + qm * 8);
    af[3] = *(const bf16x8*)(xh + axnode * 64 + 32 + qm * 8);
#pragma unroll
    for (int ot = 0; ot < 8; ++ot) {
      int o0 = ot * 16;
      f32x4 acc = {0.f, 0.f, 0.f, 0.f};
#pragma unroll
      for (int kc = 0; kc < 4; ++kc) {
        bf16x8 bfr = *(const bf16x8*)(sW + (o0 + ln) * 136 + kc * 32 + qm * 8);
        acc = __builtin_amdgcn_mfma_f32_16x16x32_bf16(af[kc], bfr, acc, 0, 0, 0);
      }
      int col = o0 + ln;
      float bias = sb[col];
#pragma unroll
      for (int i = 0; i < 4; ++i) {
        int node = base + m0 + qm * 4 + i;
        if (node < N) h[node * 128 + col] = f2bf(fmaxf(acc[i] + bias, 0.f));
      }
    }
  }
}

// ======== MFMA bf16 GEMM, layer 2: z(bf16)=h@W2l^T, r(fp32)=h@W2r^T + b2 ====
__global__ __launch_bounds__(256, 3) void k_lin2(
    const unsigned short* __restrict__ h, const float* __restrict__ W2l,
    const float* __restrict__ W2r, const float* __restrict__ b2,
    unsigned short* __restrict__ zh, float* __restrict__ r, int N) {
  __shared__ __align__(16) unsigned short sW[128 * 136];
  __shared__ __align__(16) unsigned short sA[64 * 136];
  __shared__ float sb2[64];
  int t = threadIdx.x;
  if (blockIdx.x == 0 && t < 32) ((unsigned*)zh)[N * 32 + t] = 0;
  for (int i = t; i < 128 * 128; i += 256) {
    int u = i >> 7, k = i & 127;
    float w = (u < 64) ? W2l[u * 128 + k] : W2r[(u - 64) * 128 + k];
    sW[u * 136 + k] = f2bf(w);
  }
  if (t < 64) sb2[t] = b2[t];
  int lane = t & 63, qm = lane >> 4, ln = lane & 15;
  int m0 = (t >> 6) * 16;
  __syncthreads();

  int ntiles = (N + 63) >> 6;
  for (int tile = blockIdx.x; tile < ntiles; tile += gridDim.x) {
    int base = tile << 6;
    for (int u = t; u < 64 * 64; u += 256) {
      int n = u >> 6, uu = u & 63;
      int node = base + n;
      unsigned v = 0;
      if (node < N) v = ((const unsigned*)h)[node * 64 + uu];
      ((unsigned*)(sA + n * 136))[uu] = v;
    }
    __syncthreads();
    bf16x8 af[4];
#pragma unroll
    for (int kc = 0; kc < 4; ++kc)
      af[kc] = *(const bf16x8*)(sA + (m0 + ln) * 136 + kc * 32 + qm * 8);
#pragma unroll
    for (int ot = 0; ot < 8; ++ot) {
      int o0 = ot * 16;
      f32x4 acc = {0.f, 0.f, 0.f, 0.f};
#pragma unroll
      for (int kc = 0; kc < 4; ++kc) {
        bf16x8 bfr = *(const bf16x8*)(sW + (o0 + ln) * 136 + kc * 32 + qm * 8);
        acc = __builtin_amdgcn_mfma_f32_16x16x32_bf16(af[kc], bfr, acc, 0, 0, 0);
      }
      int u = o0 + ln;
#pragma unroll
      for (int i = 0; i < 4; ++i) {
        int node = base + m0 + qm * 4 + i;
        if (node < N) {
          if (u < 64) zh[node * 64 + u] = f2bf(acc[i]);
          else        r[node * 64 + (u - 64)] = acc[i] + sb2[u - 64];
        }
      }
    }
    __syncthreads();
  }
}

// ======== gather 2 + parallel epilogue: all 64 lanes sigmoid 1 channel ======
__global__ __launch_bounds__(256) void k_gather2b(const uint4* __restrict__ zh4,
                                                  const float* __restrict__ r,
                                                  const int* __restrict__ csr,
                                                  const int* __restrict__ row_start,
                                                  const int* __restrict__ rend,
                                                  const float* __restrict__ invd,
                                                  float* __restrict__ out, int N) {
  int wid = (blockIdx.x * blockDim.x + threadIdx.x) >> 6;
  int lane = threadIdx.x & 63;
  if (wid >= N) return;
  int rq = lane >> 3, cq = lane & 7;
  int j = row_start[wid], end = rend[wid];
  float a0 = 0, a1 = 0, a2 = 0, a3 = 0, a4 = 0, a5 = 0, a6 = 0, a7 = 0;
#pragma unroll 2
  for (; j < end; j += 8) {
    int s = csr[j + rq];
    uint4 v = zh4[s * 8 + cq];
    a0 += bf2f(v.x & 0xffffu); a1 += bf2f(v.x >> 16);
    a2 += bf2f(v.y & 0xffffu); a3 += bf2f(v.y >> 16);
    a4 += bf2f(v.z & 0xffffu); a5 += bf2f(v.z >> 16);
    a6 += bf2f(v.w & 0xffffu); a7 += bf2f(v.w >> 16);
  }
  RED8(8) RED8(16) RED8(32)
  // after butterfly every lane holds full sums for channels 8cq..8cq+7;
  // lane handles channel c = 8*cq + rq via 7-cndmask select of a[rq]
  bool s0 = (rq & 1) != 0, s1 = (rq & 2) != 0, s2 = (rq & 4) != 0;
  float t0 = s0 ? a1 : a0, t1 = s0 ? a3 : a2;
  float t2 = s0 ? a5 : a4, t3 = s0 ? a7 : a6;
  float u0 = s1 ? t1 : t0, u1 = s1 ? t3 : t2;
  float vsum = s2 ? u1 : u0;
  int c = cq * 8 + rq;
  float pre = vsum * invd[wid] + r[wid * 64 + c];
  out[wid * 64 + c] = 1.0f / (1.0f + __expf(-pre));
}

extern "C" void kernel_launch(void* const* d_in, const int* in_sizes, int n_in,
                              void* d_out, int out_size, void* d_ws, size_t ws_size,
                              hipStream_t stream) {
  const float* x   = (const float*)d_in[0];
  const int*   ei  = (const int*)d_in[1];
  const float* W1l = (const float*)d_in[2];
  const float* W1r = (const float*)d_in[3];
  const float* b1  = (const float*)d_in[4];
  const float* W2l = (const float*)d_in[5];
  const float* W2r = (const float*)d_in[6];
  const float* b2  = (const float*)d_in[7];
  float* out = (float*)d_out;

  int N = in_sizes[0] / IN_C;
  int E = in_sizes[1] / 2;
  const int* src = ei;
  const int* dst = ei + E;

  // ws: [bh 256*GS][gcur 256*GS][bstart 256][rstart 256][csr E+256*4096]
  //     [row_start N][rend N][invd N]
  //     [xh (N+1)*64 bf16][zh (N+1)*64 bf16][r N*64 f][h N*128 bf16]
  //     ebuf (<=14.8MB) aliases zh+r (38.4MB), dead before k_lin2 writes them
  char* ws = (char*)d_ws;
  size_t off = 0;
  auto alignup = [](size_t v) { return (v + 511) & ~(size_t)511; };
  int* bh = (int*)(ws + off);         off = alignup(off + NBK * GS * 4);
  int* gcur = (int*)(ws + off);       off = alignup(off + NBK * GS * 4);
  int* bstart = (int*)(ws + off);     off = alignup(off + NBK * 4);
  int* rstart = (int*)(ws + off);     off = alignup(off + NBK * 4);
  int* csr = (int*)(ws + off);        off = alignup(off + ((size_t)E + NBK * 4096) * 4);
  int* row_start = (int*)(ws + off);  off = alignup(off + (size_t)N * 4);
  int* rend = (int*)(ws + off);       off = alignup(off + (size_t)N * 4);
  float* invd = (float*)(ws + off);   off = alignup(off + (size_t)N * 4);
  unsigned short* xh = (unsigned short*)(ws + off); off = alignup(off + (size_t)(N + 1) * 64 * 2);
  unsigned short* zh = (unsigned short*)(ws + off); off = alignup(off + (size_t)(N + 1) * 64 * 2);
  float* rbuf = (float*)(ws + off);   off = alignup(off + (size_t)N * 64 * 4);
  unsigned short* hbuf = (unsigned short*)(ws + off);
  int* ebuf = (int*)zh;  // spans zh+rbuf (38.4MB >= 14.8MB worst-case region)

  hipMemsetAsync(bh, 0, NBK * GS * 4, stream);
  k_xb<<<3072, 256, 0, stream>>>(dst, bh, (const float4*)x, (uint2*)xh,
                                 E, N * 16, (N + 1) * 16);
  k_bscan<<<1, NBK, 0, stream>>>(bh, bstart, rstart, gcur);
  k_msplit<<<512, 256, 0, stream>>>(src, dst, gcur, ebuf, E);
  k_localcsr<<<NBK, 512, 0, stream>>>(ebuf, bstart, gcur, rstart, csr,
                                      row_start, rend, invd, N);

  k_gl1<<<768, 256, 0, stream>>>(xh, csr, row_start, rend, invd,
                                 W1l, W1r, b1, hbuf, N);
  k_lin2<<<768, 256, 0, stream>>>(hbuf, W2l, W2r, b2, zh, rbuf, N);
  k_gather2b<<<(N + 3) / 4, 256, 0, stream>>>((const uint4*)zh, rbuf, csr,
                                              row_start, rend, invd, out, N);
}

// Round 14
// 298.597 us; speedup vs baseline: 1.1839x; 1.1839x over previous
//
#include <hip/hip_runtime.h>
#include <math.h>

#define IN_C 64
#define HID_C 128
#define OUT_C 64
#define NBK 256   // buckets of 512 nodes: bucket = dst >> 9
#define BD 64     // msplit bin ring depth
#define GS 16     // global atomic counter stride (ints) -> one 64B line each
// packed edge = (src<<9)|(dst&511); sentinel -1 unreachable (src <= N < 2^17).
// CSR rows padded to 8-multiples with dummy src = N (row N of xh/zh zeroed).

typedef __attribute__((ext_vector_type(8))) short bf16x8;   // 8 bf16 (4 VGPRs)
typedef __attribute__((ext_vector_type(4))) float f32x4;    // mfma C/D

__device__ __forceinline__ unsigned short f2bf(float f) {
  unsigned u = __float_as_uint(f);
  u = (u + 0x7FFFu + ((u >> 16) & 1u)) >> 16;  // RNE
  return (unsigned short)u;
}
__device__ __forceinline__ float bf2f(unsigned v) {  // low 16 bits = bf16
  return __uint_as_float(v << 16);
}
__device__ __forceinline__ unsigned pack2(float a, float b) {
  return (unsigned)f2bf(a) | ((unsigned)f2bf(b) << 16);
}

#define RED8(d)                                               \
  a0 += __shfl_xor(a0, d); a1 += __shfl_xor(a1, d);           \
  a2 += __shfl_xor(a2, d); a3 += __shfl_xor(a3, d);           \
  a4 += __shfl_xor(a4, d); a5 += __shfl_xor(a5, d);           \
  a6 += __shfl_xor(a6, d); a7 += __shfl_xor(a7, d);

// ======== fused: bhist (blocks 0..1023) + x->bf16 cast (blocks 1024..3071) ===
__global__ __launch_bounds__(256) void k_xb(const int* __restrict__ dst,
                                            int* __restrict__ bh,
                                            const float4* __restrict__ x4,
                                            uint2* __restrict__ xh2,
                                            int E, int Mreal, int Mtot) {
  __shared__ int hh[NBK];
  int t = threadIdx.x;
  if (blockIdx.x < 1024) {
    hh[t] = 0;
    __syncthreads();
    for (int e = blockIdx.x * 256 + t; e < E; e += 1024 * 256)
      atomicAdd(&hh[dst[e] >> 9], 1);
    __syncthreads();
    if (hh[t]) atomicAdd(&bh[t * GS], hh[t]);
  } else {
    int b = blockIdx.x - 1024;
    for (int i = b * 256 + t; i < Mtot; i += 2048 * 256) {
      uint2 p = {0u, 0u};
      if (i < Mreal) {
        float4 v = x4[i];
        p.x = pack2(v.x, v.y);
        p.y = pack2(v.z, v.w);
      }
      xh2[i] = p;
    }
  }
}

// ======== scan: ebuf chunked-region starts + padded csr starts ========
__global__ __launch_bounds__(256) void k_bscan(const int* __restrict__ bh,
                                               int* __restrict__ bstart,
                                               int* __restrict__ rstart,
                                               int* __restrict__ gcur) {
  __shared__ int s1[NBK], s2[NBK];
  int t = threadIdx.x;
  int cnt = bh[t * GS];
  int region = 16 * min(cnt, (cnt >> 4) + 512);
  int creg = cnt + 4096;
  s1[t] = region; s2[t] = creg;
  __syncthreads();
  for (int off = 1; off < NBK; off <<= 1) {
    int a1 = (t >= off) ? s1[t - off] : 0;
    int a2 = (t >= off) ? s2[t - off] : 0;
    __syncthreads();
    s1[t] += a1; s2[t] += a2;
    __syncthreads();
  }
  int ex1 = s1[t] - region;
  int ex2 = s2[t] - creg;
  bstart[t] = ex1; gcur[t * GS] = ex1; rstart[t] = ex2;
}

// ======== multisplit: transposed ring bins, line-padded cursors, 8-fetch ====
__global__ __launch_bounds__(256) void k_msplit(const int* __restrict__ src,
                                                const int* __restrict__ dst,
                                                int* __restrict__ gcur,
                                                int* __restrict__ ebuf, int E) {
  __shared__ int bcnt[NBK], bhead[NBK];
  __shared__ int bins[BD][NBK];
  int t = threadIdx.x;
  bcnt[t] = 0; bhead[t] = 0;
  int per = (E + gridDim.x - 1) / gridDim.x;
  int e0 = blockIdx.x * per, e1 = min(E, e0 + per);
  int e = e0 + t;
  int pb[8], pv[8]; int pc = 0;
  __syncthreads();
  for (;;) {
    while (pc < 8 && e < e1) {
      int d = dst[e], s = src[e];
      pb[pc] = d >> 9; pv[pc] = (s << 9) | (d & 511);
      pc++; e += 256;
    }
    for (int q = pc - 1; q >= 0; --q) {
      int pos = atomicAdd(&bcnt[pb[q]], 1);
      if (pos < BD) {
        bins[(bhead[pb[q]] + pos) & (BD - 1)][pb[q]] = pv[q];
        pc--;
        if (q != pc) { pb[q] = pb[pc]; pv[q] = pv[pc]; }
      }
    }
    int pending = __syncthreads_count(pc > 0 || e < e1);
    int cntv = min(bcnt[t], BD);
    int head = bhead[t];
    while (cntv >= 16) {
      int base = atomicAdd(&gcur[t * GS], 16);
      int4 o[4];
#pragma unroll
      for (int k = 0; k < 16; ++k)
        ((int*)o)[k] = bins[(head + k) & (BD - 1)][t];
      int4* g = (int4*)(ebuf + base);
      g[0] = o[0]; g[1] = o[1]; g[2] = o[2]; g[3] = o[3];
      head = (head + 16) & (BD - 1);
      cntv -= 16;
    }
    bhead[t] = head;
    bcnt[t] = cntv;
    __syncthreads();
    if (!pending) break;
  }
  int cntv = bcnt[t];
  if (cntv > 0) {
    int head = bhead[t];
    int base = atomicAdd(&gcur[t * GS], 16);
#pragma unroll
    for (int k = 0; k < 16; ++k)
      ebuf[base + k] = (k < cntv) ? bins[(head + k) & (BD - 1)][t] : -1;
  }
}

// ======== per-bucket local CSR (512 nodes/bucket), 8-padded rows ========
__global__ __launch_bounds__(512) void k_localcsr(const int* __restrict__ ebuf,
                                                  const int* __restrict__ bstart,
                                                  const int* __restrict__ gcur,
                                                  const int* __restrict__ rstart,
                                                  int* __restrict__ csr,
                                                  int* __restrict__ row_start,
                                                  int* __restrict__ rend,
                                                  float* __restrict__ invd, int N) {
  __shared__ int lcnt[512], loff[512], lcur[512];
  int t = threadIdx.x, b = blockIdx.x;
  int start = bstart[b], endp = gcur[b * GS], rs = rstart[b];
  lcnt[t] = 0;
  __syncthreads();
  for (int i = start + t; i < endp; i += 512) {
    int pe = ebuf[i];
    if (pe != -1) atomicAdd(&lcnt[pe & 511], 1);
  }
  __syncthreads();
  int v = lcnt[t];
  int pvn = (v + 7) & ~7;
  loff[t] = pvn;
  __syncthreads();
  for (int off = 1; off < 512; off <<= 1) {
    int a = (t >= off) ? loff[t - off] : 0;
    __syncthreads();
    loff[t] += a;
    __syncthreads();
  }
  int ex = loff[t] - pvn;
  lcur[t] = ex;
  int node = (b << 9) + t;
  if (node < N) {
    row_start[node] = rs + ex;
    rend[node] = rs + ex + pvn;
    invd[node] = 1.0f / fmaxf((float)v, 1.0f);
  }
  __syncthreads();
  for (int i = start + t; i < endp; i += 512) {
    int pe = ebuf[i];
    if (pe != -1) {
      int pos = atomicAdd(&lcur[pe & 511], 1);
      csr[rs + pos] = pe >> 9;
    }
  }
  for (int k = ex + v; k < ex + pvn; ++k) csr[rs + k] = N;
}

// ======== gather 1: branch-free, 8-lane x uint4 rows, bf16 in/out ========
__global__ __launch_bounds__(256) void k_gather1(const uint4* __restrict__ xh4,
                                                 const int* __restrict__ csr,
                                                 const int* __restrict__ row_start,
                                                 const int* __restrict__ rend,
                                                 const float* __restrict__ invd,
                                                 uint4* __restrict__ aggh4, int N) {
  int wid = (blockIdx.x * blockDim.x + threadIdx.x) >> 6;
  int lane = threadIdx.x & 63;
  if (wid >= N) return;
  int rq = lane >> 3, cq = lane & 7;
  int j = row_start[wid], end = rend[wid];
  float a0 = 0, a1 = 0, a2 = 0, a3 = 0, a4 = 0, a5 = 0, a6 = 0, a7 = 0;
#pragma unroll 2
  for (; j < end; j += 8) {
    int s = csr[j + rq];
    uint4 v = xh4[s * 8 + cq];
    a0 += bf2f(v.x & 0xffffu); a1 += bf2f(v.x >> 16);
    a2 += bf2f(v.y & 0xffffu); a3 += bf2f(v.y >> 16);
    a4 += bf2f(v.z & 0xffffu); a5 += bf2f(v.z >> 16);
    a6 += bf2f(v.w & 0xffffu); a7 += bf2f(v.w >> 16);
  }
  RED8(8) RED8(16) RED8(32)
  if (rq == 0) {
    float inv = invd[wid];
    uint4 p;
    p.x = pack2(a0 * inv, a1 * inv);
    p.y = pack2(a2 * inv, a3 * inv);
    p.z = pack2(a4 * inv, a5 * inv);
    p.w = pack2(a6 * inv, a7 * inv);
    aggh4[wid * 8 + cq] = p;
  }
}

// ======== MFMA bf16 GEMM, layer 1: h(bf16) = relu([agg|x]@[W1l|W1r]^T + b1) ===
__global__ __launch_bounds__(256, 3) void k_lin1(
    const unsigned short* __restrict__ aggh, const unsigned short* __restrict__ xh,
    const float* __restrict__ W1l, const float* __restrict__ W1r,
    const float* __restrict__ b1, unsigned short* __restrict__ h, int N) {
  __shared__ __align__(16) unsigned short sW[128 * 136];
  __shared__ __align__(16) unsigned short sA[64 * 136];
  __shared__ float sb[128];
  int t = threadIdx.x;
  for (int i = t; i < 128 * 128; i += 256) {
    int o = i >> 7, k = i & 127;
    float w = (k < 64) ? W1l[o * 64 + k] : W1r[o * 64 + (k - 64)];
    sW[o * 136 + k] = f2bf(w);
  }
  if (t < 128) sb[t] = b1[t];
  int lane = t & 63, qm = lane >> 4, ln = lane & 15;
  int m0 = (t >> 6) * 16;
  __syncthreads();

  int ntiles = (N + 63) >> 6;
  for (int tile = blockIdx.x; tile < ntiles; tile += gridDim.x) {
    int base = tile << 6;
    for (int u = t; u < 64 * 64; u += 256) {
      int n = u >> 6, uu = u & 63;
      int node = base + n;
      unsigned v = 0;
      if (node < N) v = (uu < 32) ? ((const unsigned*)aggh)[node * 32 + uu]
                                  : ((const unsigned*)xh)[node * 32 + (uu - 32)];
      ((unsigned*)(sA + n * 136))[uu] = v;
    }
    __syncthreads();
    bf16x8 af[4];
#pragma unroll
    for (int kc = 0; kc < 4; ++kc)
      af[kc] = *(const bf16x8*)(sA + (m0 + ln) * 136 + kc * 32 + qm * 8);
#pragma unroll
    for (int ot = 0; ot < 8; ++ot) {
      int o0 = ot * 16;
      f32x4 acc = {0.f, 0.f, 0.f, 0.f};
#pragma unroll
      for (int kc = 0; kc < 4; ++kc) {
        bf16x8 bfr = *(const bf16x8*)(sW + (o0 + ln) * 136 + kc * 32 + qm * 8);
        acc = __builtin_amdgcn_mfma_f32_16x16x32_bf16(af[kc], bfr, acc, 0, 0, 0);
      }
      int col = o0 + ln;
      float bias = sb[col];
#pragma unroll
      for (int i = 0; i < 4; ++i) {
        int node = base + m0 + qm * 4 + i;
        if (node < N) h[node * 128 + col] = f2bf(fmaxf(acc[i] + bias, 0.f));
      }
    }
    __syncthreads();
  }
}

// ======== MFMA bf16 GEMM, layer 2: z(bf16)=h@W2l^T, r(fp32)=h@W2r^T + b2 ====
__global__ __launch_bounds__(256, 3) void k_lin2(
    const unsigned short* __restrict__ h, const float* __restrict__ W2l,
    const float* __restrict__ W2r, const float* __restrict__ b2,
    unsigned short* __restrict__ zh, float* __restrict__ r, int N) {
  __shared__ __align__(16) unsigned short sW[128 * 136];
  __shared__ __align__(16) unsigned short sA[64 * 136];
  __shared__ float sb2[64];
  int t = threadIdx.x;
  if (blockIdx.x == 0 && t < 32) ((unsigned*)zh)[N * 32 + t] = 0;
  for (int i = t; i < 128 * 128; i += 256) {
    int u = i >> 7, k = i & 127;
    float w = (u < 64) ? W2l[u * 128 + k] : W2r[(u - 64) * 128 + k];
    sW[u * 136 + k] = f2bf(w);
  }
  if (t < 64) sb2[t] = b2[t];
  int lane = t & 63, qm = lane >> 4, ln = lane & 15;
  int m0 = (t >> 6) * 16;
  __syncthreads();

  int ntiles = (N + 63) >> 6;
  for (int tile = blockIdx.x; tile < ntiles; tile += gridDim.x) {
    int base = tile << 6;
    for (int u = t; u < 64 * 64; u += 256) {
      int n = u >> 6, uu = u & 63;
      int node = base + n;
      unsigned v = 0;
      if (node < N) v = ((const unsigned*)h)[node * 64 + uu];
      ((unsigned*)(sA + n * 136))[uu] = v;
    }
    __syncthreads();
    bf16x8 af[4];
#pragma unroll
    for (int kc = 0; kc < 4; ++kc)
      af[kc] = *(const bf16x8*)(sA + (m0 + ln) * 136 + kc * 32 + qm * 8);
#pragma unroll
    for (int ot = 0; ot < 8; ++ot) {
      int o0 = ot * 16;
      f32x4 acc = {0.f, 0.f, 0.f, 0.f};
#pragma unroll
      for (int kc = 0; kc < 4; ++kc) {
        bf16x8 bfr = *(const bf16x8*)(sW + (o0 + ln) * 136 + kc * 32 + qm * 8);
        acc = __builtin_amdgcn_mfma_f32_16x16x32_bf16(af[kc], bfr, acc, 0, 0, 0);
      }
      int u = o0 + ln;
#pragma unroll
      for (int i = 0; i < 4; ++i) {
        int node = base + m0 + qm * 4 + i;
        if (node < N) {
          if (u < 64) zh[node * 64 + u] = f2bf(acc[i]);
          else        r[node * 64 + (u - 64)] = acc[i] + sb2[u - 64];
        }
      }
    }
    __syncthreads();
  }
}

// ======== gather 2 + parallel epilogue: all 64 lanes sigmoid 1 channel ======
__global__ __launch_bounds__(256) void k_gather2b(const uint4* __restrict__ zh4,
                                                  const float* __restrict__ r,
                                                  const int* __restrict__ csr,
                                                  const int* __restrict__ row_start,
                                                  const int* __restrict__ rend,
                                                  const float* __restrict__ invd,
                                                  float* __restrict__ out, int N) {
  int wid = (blockIdx.x * blockDim.x + threadIdx.x) >> 6;
  int lane = threadIdx.x & 63;
  if (wid >= N) return;
  int rq = lane >> 3, cq = lane & 7;
  int j = row_start[wid], end = rend[wid];
  float a0 = 0, a1 = 0, a2 = 0, a3 = 0, a4 = 0, a5 = 0, a6 = 0, a7 = 0;
#pragma unroll 2
  for (; j < end; j += 8) {
    int s = csr[j + rq];
    uint4 v = zh4[s * 8 + cq];
    a0 += bf2f(v.x & 0xffffu); a1 += bf2f(v.x >> 16);
    a2 += bf2f(v.y & 0xffffu); a3 += bf2f(v.y >> 16);
    a4 += bf2f(v.z & 0xffffu); a5 += bf2f(v.z >> 16);
    a6 += bf2f(v.w & 0xffffu); a7 += bf2f(v.w >> 16);
  }
  RED8(8) RED8(16) RED8(32)
  // after butterfly every lane holds full sums for channels 8cq..8cq+7;
  // lane handles channel c = 8*cq + rq via 7-cndmask select of a[rq]
  bool s0 = (rq & 1) != 0, s1 = (rq & 2) != 0, s2 = (rq & 4) != 0;
  float t0 = s0 ? a1 : a0, t1 = s0 ? a3 : a2;
  float t2 = s0 ? a5 : a4, t3 = s0 ? a7 : a6;
  float u0 = s1 ? t1 : t0, u1 = s1 ? t3 : t2;
  float vsum = s2 ? u1 : u0;
  int c = cq * 8 + rq;
  float pre = vsum * invd[wid] + r[wid * 64 + c];
  out[wid * 64 + c] = 1.0f / (1.0f + __expf(-pre));
}

extern "C" void kernel_launch(void* const* d_in, const int* in_sizes, int n_in,
                              void* d_out, int out_size, void* d_ws, size_t ws_size,
                              hipStream_t stream) {
  const float* x   = (const float*)d_in[0];
  const int*   ei  = (const int*)d_in[1];
  const float* W1l = (const float*)d_in[2];
  const float* W1r = (const float*)d_in[3];
  const float* b1  = (const float*)d_in[4];
  const float* W2l = (const float*)d_in[5];
  const float* W2r = (const float*)d_in[6];
  const float* b2  = (const float*)d_in[7];
  float* out = (float*)d_out;

  int N = in_sizes[0] / IN_C;
  int E = in_sizes[1] / 2;
  const int* src = ei;
  const int* dst = ei + E;

  // ws: [bh 256*GS][gcur 256*GS][bstart 256][rstart 256][csr E+256*4096]
  //     [row_start N][rend N][invd N]
  //     [xh (N+1)*64 bf16][aggh N*64 bf16][zh (N+1)*64 bf16]  (ebuf aliases aggh+zh)
  //     [r N*64 f][h N*128 bf16]
  char* ws = (char*)d_ws;
  size_t off = 0;
  auto alignup = [](size_t v) { return (v + 511) & ~(size_t)511; };
  int* bh = (int*)(ws + off);         off = alignup(off + NBK * GS * 4);
  int* gcur = (int*)(ws + off);       off = alignup(off + NBK * GS * 4);
  int* bstart = (int*)(ws + off);     off = alignup(off + NBK * 4);
  int* rstart = (int*)(ws + off);     off = alignup(off + NBK * 4);
  int* csr = (int*)(ws + off);        off = alignup(off + ((size_t)E + NBK * 4096) * 4);
  int* row_start = (int*)(ws + off);  off = alignup(off + (size_t)N * 4);
  int* rend = (int*)(ws + off);       off = alignup(off + (size_t)N * 4);
  float* invd = (float*)(ws + off);   off = alignup(off + (size_t)N * 4);
  unsigned short* xh = (unsigned short*)(ws + off);   off = alignup(off + (size_t)(N + 1) * 64 * 2);
  unsigned short* aggh = (unsigned short*)(ws + off); off = alignup(off + (size_t)N * 64 * 2);
  unsigned short* zh = (unsigned short*)(ws + off);   off = alignup(off + (size_t)(N + 1) * 64 * 2);
  float* rbuf = (float*)(ws + off);   off = alignup(off + (size_t)N * 64 * 4);
  unsigned short* hbuf = (unsigned short*)(ws + off);
  int* ebuf = (int*)aggh;  // spans aggh+zh (~25.6MB >= 14.8MB worst-case region);
                           // dead before k_gather1 / k_lin2 write them

  hipMemsetAsync(bh, 0, NBK * GS * 4, stream);
  k_xb<<<3072, 256, 0, stream>>>(dst, bh, (const float4*)x, (uint2*)xh,
                                 E, N * 16, (N + 1) * 16);
  k_bscan<<<1, NBK, 0, stream>>>(bh, bstart, rstart, gcur);
  k_msplit<<<512, 256, 0, stream>>>(src, dst, gcur, ebuf, E);
  k_localcsr<<<NBK, 512, 0, stream>>>(ebuf, bstart, gcur, rstart, csr,
                                      row_start, rend, invd, N);

  k_gather1<<<(N + 3) / 4, 256, 0, stream>>>((const uint4*)xh, csr, row_start,
                                             rend, invd, (uint4*)aggh, N);
  k_lin1<<<768, 256, 0, stream>>>(aggh, xh, W1l, W1r, b1, hbuf, N);
  k_lin2<<<768, 256, 0, stream>>>(hbuf, W2l, W2r, b2, zh, rbuf, N);
  k_gather2b<<<(N + 3) / 4, 256, 0, stream>>>((const uint4*)zh, rbuf, csr,
                                              row_start, rend, invd, out, N);
}